// Round 1
// baseline (89.745 us; speedup 1.0000x reference)
//
#include <hip/hip_runtime.h>
#include <math.h>
#include <float.h>

// ChamferLoss: set1/set2 [8, 4096, 3] fp32 -> scalar
// out = sum over both directions of per-point min distances / (8*4096*4096)
//
// Inner loop uses d^2 = ||q||^2 + (||p||^2 - 2 q.p); ||p||^2 staged in LDS as
// the .w of a float4 per point, ||q||^2 added after the min (query-constant).
//
// v2: QPT 4 -> 8 (each ds_read_b128 of a point feeds 8 query FMA chains,
// halving LDS-pipe cycles per pair-eval: LDS floor 20.5us -> 10.2us per CU),
// THREADS 512 -> 1024 so the QB=256 grid (256 blocks = 1/CU) still gives
// 16 waves/CU. Min trees written as fmin(fmin(a,b),c) to fuse into v_min3_f32.

#define BATCH   8
#define NPTS    4096
#define THREADS 1024
#define QB      256          // queries per block (32 lanes * QPT)
#define QPT     8            // queries per thread
#define NGRP    32           // scan groups (THREADS/32)
#define PPG     (NPTS/NGRP)  // 128 points scanned per group

__global__ __launch_bounds__(THREADS, 4)
void chamfer_main(const float* __restrict__ set1,
                  const float* __restrict__ set2,
                  float* __restrict__ out)
{
    __shared__ float4 dbp[NPTS];          // 64 KB: {x,y,z,||p||^2} per point
    __shared__ float  part[NGRP][QB];     // 32 KB: per-group partial mins

    const int blk = blockIdx.x;           // 0..255
    const int dir = blk >> 7;             // 0: set1->set2, 1: set2->set1
    const int rem = blk & 127;
    const int b   = rem >> 4;             // batch 0..7
    const int qb  = rem & 15;             // query block 0..15

    const float* __restrict__ Q  = dir ? set2 : set1;
    const float* __restrict__ DB = dir ? set1 : set2;
    const float* __restrict__ DBb = DB + (size_t)b * NPTS * 3;

    const int t = threadIdx.x;

    // --- stage DB batch into LDS with precomputed ||p||^2 ---
    for (int i = t; i < NPTS; i += THREADS) {
        const float x = DBb[3 * i + 0];
        const float y = DBb[3 * i + 1];
        const float z = DBb[3 * i + 2];
        dbp[i] = make_float4(x, y, z, fmaf(x, x, fmaf(y, y, z * z)));
    }

    // --- this thread's 8 query coefficient sets (-2*q) ---
    const int l = t & 31;                 // lane-in-group
    const int g = t >> 5;                 // scan group 0..31
    const int qbase = qb * QB;

    float qa[QPT], qbc[QPT], qc[QPT], dmin[QPT];
    #pragma unroll
    for (int j = 0; j < QPT; ++j) {
        const float* qp = Q + ((size_t)b * NPTS + qbase + l + 32 * j) * 3;
        qa[j]  = -2.0f * qp[0];
        qbc[j] = -2.0f * qp[1];
        qc[j]  = -2.0f * qp[2];
        dmin[j] = FLT_MAX;
    }

    __syncthreads();

    // --- scan this group's 128 points for 8 queries ---
    const float4* __restrict__ s4 = dbp + g * PPG;

    #pragma unroll 2
    for (int c = 0; c < PPG / 4; ++c) {
        const float4 P0 = s4[c * 4 + 0];
        const float4 P1 = s4[c * 4 + 1];
        const float4 P2 = s4[c * 4 + 2];
        const float4 P3 = s4[c * 4 + 3];
        #pragma unroll
        for (int j = 0; j < QPT; ++j) {
            const float a = qa[j], bb = qbc[j], cc = qc[j];
            float d0 = fmaf(a, P0.x, fmaf(bb, P0.y, fmaf(cc, P0.z, P0.w)));
            float d1 = fmaf(a, P1.x, fmaf(bb, P1.y, fmaf(cc, P1.z, P1.w)));
            float d2 = fmaf(a, P2.x, fmaf(bb, P2.y, fmaf(cc, P2.z, P2.w)));
            float d3 = fmaf(a, P3.x, fmaf(bb, P3.y, fmaf(cc, P3.z, P3.w)));
            // two v_min3_f32 candidates: min3(d0,d1,d2), min3(m1,d3,dmin)
            const float m1 = fminf(fminf(d0, d1), d2);
            dmin[j] = fminf(fminf(m1, d3), dmin[j]);
        }
    }

    // --- write per-group partial mins ---
    #pragma unroll
    for (int j = 0; j < QPT; ++j)
        part[g][l + 32 * j] = dmin[j];
    __syncthreads();

    // --- combine groups, finish d = sqrt(max(q^2 + m, 0)), reduce sum ---
    float dist = 0.0f;
    if (t < QB) {
        float m = part[0][t];
        #pragma unroll
        for (int gg = 1; gg < NGRP; ++gg)
            m = fminf(m, part[gg][t]);
        const float* qp = Q + ((size_t)b * NPTS + qbase + t) * 3;
        const float qx = qp[0], qy = qp[1], qz = qp[2];
        const float q2 = fmaf(qx, qx, fmaf(qy, qy, qz * qz));
        dist = sqrtf(fmaxf(q2 + m, 0.0f));
    }

    // wave reduce (only waves 0..3 have nonzero), one atomic per wave
    #pragma unroll
    for (int off = 32; off > 0; off >>= 1)
        dist += __shfl_down(dist, off);
    if (t < QB && (t & 63) == 0)
        atomicAdd(out, dist * (1.0f / (float)((size_t)BATCH * NPTS * NPTS)));
}

extern "C" void kernel_launch(void* const* d_in, const int* in_sizes, int n_in,
                              void* d_out, int out_size, void* d_ws, size_t ws_size,
                              hipStream_t stream) {
    const float* s1 = (const float*)d_in[0];
    const float* s2 = (const float*)d_in[1];
    float* out = (float*)d_out;

    hipMemsetAsync(out, 0, sizeof(float), stream);  // d_out poisoned 0xAA each call
    chamfer_main<<<dim3(256), dim3(THREADS), 0, stream>>>(s1, s2, out);
}